// Round 1
// baseline (2423.404 us; speedup 1.0000x reference)
//
#include <hip/hip_runtime.h>
#include <math.h>

#define BB 2
#define CIN 3
#define IMGS 256
#define PS 16
#define GG 16
#define NN 256
#define DIM 768
#define NH 12
#define DHD 64
#define NL 8
#define FFD 2048
#define LNEPS 1e-5f

// ---- gemm mode flags ----
#define MB    1   // add bias[col]
#define MB2   2   // bias * 2 (implies bias)
#define MPOS  4   // add pos_embed[(row%256)*N + col]
#define MRELU 8
#define MRES  16  // C += result (residual)
#define MSUM2 32  // A-load = A + A2

// C[M,N] = A[M,K] * B[N,K]^T (+ epilogues). All of M%64==0, N%64==0, K%16==0.
template<int MODE>
__global__ __launch_bounds__(256) void gemm_nt(
    const float* __restrict__ A, const float* __restrict__ A2,
    const float* __restrict__ B, const float* __restrict__ bias,
    const float* __restrict__ pos, float* __restrict__ C,
    int M, int N, int K, int zdiv,
    long long sAo, long long sBi, long long sCo, long long sCi)
{
    int z = blockIdx.z;
    int zo = z / zdiv, zi = z % zdiv;
    A += zo * sAo;
    if (MODE & MSUM2) A2 += zo * sAo;
    B += zi * sBi;
    long long coff = zo * sCo + zi * sCi;

    __shared__ float As[16][68], Bs[16][68];
    int tid = threadIdx.x;
    int tx = tid & 15, ty = tid >> 4;
    int lr = tid >> 2;          // 0..63: tile row for loading
    int lc = (tid & 3) << 2;    // 0,4,8,12: k offset for loading
    int bm = blockIdx.y * 64, bn = blockIdx.x * 64;

    float acc[4][4] = {};

    for (int k0 = 0; k0 < K; k0 += 16) {
        float4 av = *(const float4*)(A + (size_t)(bm + lr) * K + k0 + lc);
        if (MODE & MSUM2) {
            float4 a2 = *(const float4*)(A2 + (size_t)(bm + lr) * K + k0 + lc);
            av.x += a2.x; av.y += a2.y; av.z += a2.z; av.w += a2.w;
        }
        float4 bv = *(const float4*)(B + (size_t)(bn + lr) * K + k0 + lc);
        As[lc+0][lr] = av.x; As[lc+1][lr] = av.y; As[lc+2][lr] = av.z; As[lc+3][lr] = av.w;
        Bs[lc+0][lr] = bv.x; Bs[lc+1][lr] = bv.y; Bs[lc+2][lr] = bv.z; Bs[lc+3][lr] = bv.w;
        __syncthreads();
        #pragma unroll
        for (int kk = 0; kk < 16; ++kk) {
            float ra[4], rb[4];
            *(float4*)ra = *(const float4*)(&As[kk][ty * 4]);
            *(float4*)rb = *(const float4*)(&Bs[kk][tx * 4]);
            #pragma unroll
            for (int i = 0; i < 4; ++i)
                #pragma unroll
                for (int j = 0; j < 4; ++j)
                    acc[i][j] += ra[i] * rb[j];
        }
        __syncthreads();
    }

    #pragma unroll
    for (int i = 0; i < 4; ++i) {
        int r = bm + ty * 4 + i;
        #pragma unroll
        for (int j = 0; j < 4; ++j) {
            int c = bn + tx * 4 + j;
            float v = acc[i][j];
            if (MODE & (MB | MB2)) v += bias[c] * ((MODE & MB2) ? 2.f : 1.f);
            if (MODE & MPOS) v += pos[(size_t)(r & (NN - 1)) * N + c];
            if (MODE & MRELU) v = fmaxf(v, 0.f);
            size_t ci = coff + (size_t)r * N + c;
            if (MODE & MRES) C[ci] += v; else C[ci] = v;
        }
    }
}

// patches[b*256+n][k] = x[b][c][gy*16+py][gx*16+px], n=gy*16+gx, k=c*256+py*16+px
__global__ void im2col_kernel(const float* __restrict__ x, float* __restrict__ patches)
{
    int idx = blockIdx.x * 256 + threadIdx.x;   // < 2*256*768
    int k = idx % DIM;
    int m = idx / DIM;
    int b = m >> 8, n = m & 255;
    int gy = n >> 4, gx = n & 15;
    int c = k >> 8, rem = k & 255, py = rem >> 4, px = rem & 15;
    patches[idx] = x[((size_t)(b * CIN + c) * IMGS + gy * PS + py) * IMGS + gx * PS + px];
}

// Wct[dydx][oc][c] = conv1_w[oc][c][dy][dx]
__global__ void wct_kernel(const float* __restrict__ w, float* __restrict__ Wct)
{
    int idx = blockIdx.x * 256 + threadIdx.x;   // < 9*256*768
    int c = idx % DIM;
    int t = idx / DIM;
    int oc = t & 255;
    int dydx = t >> 8;
    int dy = dydx / 3, dx = dydx % 3;
    Wct[idx] = w[((size_t)(oc * DIM + c) * 3 + dy) * 3 + dx];
}

__global__ __launch_bounds__(256) void ln_kernel(
    const float* __restrict__ X, const float* __restrict__ g,
    const float* __restrict__ bta, float* __restrict__ Y)
{
    int row = blockIdx.x;
    int tid = threadIdx.x;
    const float* xp = X + (size_t)row * DIM;
    float v0 = xp[tid], v1 = xp[tid + 256], v2 = xp[tid + 512];
    float s = v0 + v1 + v2, s2 = v0 * v0 + v1 * v1 + v2 * v2;
    #pragma unroll
    for (int off = 32; off > 0; off >>= 1) {
        s  += __shfl_down(s, off);
        s2 += __shfl_down(s2, off);
    }
    __shared__ float r1[4], r2[4], mstat[2];
    if ((tid & 63) == 0) { r1[tid >> 6] = s; r2[tid >> 6] = s2; }
    __syncthreads();
    if (tid == 0) {
        float a = r1[0] + r1[1] + r1[2] + r1[3];
        float c = r2[0] + r2[1] + r2[2] + r2[3];
        float mean = a * (1.f / DIM);
        float var = c * (1.f / DIM) - mean * mean;
        mstat[0] = mean;
        mstat[1] = 1.f / sqrtf(var + LNEPS);
    }
    __syncthreads();
    float mean = mstat[0], inv = mstat[1];
    float* yp = Y + (size_t)row * DIM;
    yp[tid]       = (v0 - mean) * inv * g[tid]       + bta[tid];
    yp[tid + 256] = (v1 - mean) * inv * g[tid + 256] + bta[tid + 256];
    yp[tid + 512] = (v2 - mean) * inv * g[tid + 512] + bta[tid + 512];
}

// One block per (b, g) sequence per type. type 0: row attn (seq along gy, fixed gx=g).
// type 1: col attn (seq along gx, fixed gy=g). Loops over all 12 heads.
__global__ __launch_bounds__(256) void attn_kernel(
    const float* __restrict__ qkv, float* __restrict__ orow,
    float* __restrict__ ocol, float* __restrict__ am)
{
    int b = blockIdx.x / GG, g = blockIdx.x % GG;
    int type = blockIdx.y;
    int tid = threadIdx.x;
    __shared__ float qs[16][64], ks[16][64], vs[16][64], as_[16][17], amacc[16];
    if (tid < 16) amacc[tid] = 0.f;
    float* obuf = (type == 0) ? orow : ocol;

    for (int hh = 0; hh < NH; ++hh) {
        #pragma unroll
        for (int l = 0; l < 4; ++l) {
            int e = tid + l * 256;
            int s = e >> 6, d = e & 63;
            int n = (type == 0) ? (s * GG + g) : (g * GG + s);
            const float* base = qkv + (size_t)(b * NN + n) * (3 * DIM) + hh * 64 + d;
            qs[s][d] = base[0];
            ks[s][d] = base[DIM];
            vs[s][d] = base[2 * DIM];
        }
        __syncthreads();
        int s = tid >> 4, t = tid & 15;
        float sc = 0.f;
        #pragma unroll
        for (int d = 0; d < 64; ++d) sc += qs[s][d] * ks[t][d];
        sc *= 0.125f;
        float mx = sc;
        #pragma unroll
        for (int off = 1; off < 16; off <<= 1) mx = fmaxf(mx, __shfl_xor(mx, off, 16));
        float p = __expf(sc - mx);
        float sum = p;
        #pragma unroll
        for (int off = 1; off < 16; off <<= 1) sum += __shfl_xor(sum, off, 16);
        as_[s][t] = p / sum;
        __syncthreads();
        if (tid < 16) {
            float acc = 0.f;
            #pragma unroll
            for (int ss = 0; ss < 16; ++ss) acc += as_[ss][tid];
            amacc[tid] += acc;
        }
        int s2 = tid >> 4, dg = (tid & 15) * 4;
        float o0 = 0, o1 = 0, o2 = 0, o3 = 0;
        #pragma unroll
        for (int t2 = 0; t2 < 16; ++t2) {
            float a2 = as_[s2][t2];
            o0 += a2 * vs[t2][dg];
            o1 += a2 * vs[t2][dg + 1];
            o2 += a2 * vs[t2][dg + 2];
            o3 += a2 * vs[t2][dg + 3];
        }
        int n2 = (type == 0) ? (s2 * GG + g) : (g * GG + s2);
        float* op = obuf + (size_t)(b * NN + n2) * DIM + hh * 64 + dg;
        op[0] = o0; op[1] = o1; op[2] = o2; op[3] = o3;
        __syncthreads();
    }
    if (tid < 16)
        am[((size_t)(type * BB + b) * GG + g) * GG + tid] = amacc[tid] * (1.f / (NH * 16));
}

__global__ void div_kernel(const float* __restrict__ am, float* __restrict__ divacc)
{
    int i = blockIdx.x * 256 + threadIdx.x;     // < 512
    divacc[i] += fabsf(am[i] - am[512 + i]);
}

// hfin = h + (divacc/L)*edge_w + edge_b
__global__ void hfin_kernel(const float* __restrict__ h, const float* __restrict__ divacc,
                            const float* __restrict__ ew, const float* __restrict__ eb,
                            float* __restrict__ hf)
{
    int idx = blockIdx.x * 256 + threadIdx.x;   // < 393216
    int d = idx % DIM, m = idx / DIM;
    hf[idx] = h[idx] + divacc[m] * (1.f / NL) * ew[d] + eb[d];
}

// S[b][x][oc][dy][i] = sum over dx,j of ax(x+dx-1, j) * P[b][dy][dx][oc][i*16+j]
__global__ void s_kernel(const float* __restrict__ P, float* __restrict__ S)
{
    int idx = blockIdx.x * 256 + threadIdx.x;   // < 2*256*256*48
    int i = idx & 15;
    int dy = (idx >> 4) % 3;
    int t = idx / 48;
    int oc = t & 255;
    int x = (t >> 8) & 255;
    int b = t >> 16;
    float acc = 0.f;
    #pragma unroll
    for (int dx = 0; dx < 3; ++dx) {
        int u = x + dx - 1;
        if (u < 0 || u > 255) continue;
        float p = (u + 0.5f) * 0.0625f - 0.5f;
        float fl = floorf(p);
        float f = p - fl;
        int j0 = (int)fl;
        int ja = j0 < 0 ? 0 : j0;
        int jb = (j0 + 1 > 15) ? 15 : (j0 + 1);
        const float* Pp = P + ((((size_t)(b * 3 + dy) * 3 + dx) * 256 + oc) << 8) + (i << 4);
        acc += (1.f - f) * Pp[ja] + f * Pp[jb];
    }
    S[idx] = acc;
}

// out[b][y][x] = b2 + sum_oc w2[oc]*relu(b1[oc] + sum_dy,i ay(y+dy-1,i)*S[b][x][oc][dy][i])
__global__ __launch_bounds__(256) void out_kernel(
    const float* __restrict__ S, const float* __restrict__ b1,
    const float* __restrict__ w2, const float* __restrict__ b2p,
    float* __restrict__ out)
{
    int b = blockIdx.x >> 8, x = blockIdx.x & 255;
    __shared__ float Sl[12288];
    const float* Sp = S + (size_t)(b * 256 + x) * 12288;
    for (int l = threadIdx.x; l < 12288; l += 256) Sl[l] = Sp[l];
    __syncthreads();
    int y = threadIdx.x;
    float wy[3][2];
    int iy[3][2];
    #pragma unroll
    for (int dy = 0; dy < 3; ++dy) {
        int v = y + dy - 1;
        if (v < 0 || v > 255) {
            wy[dy][0] = wy[dy][1] = 0.f;
            iy[dy][0] = iy[dy][1] = 0;
        } else {
            float pp = (v + 0.5f) * 0.0625f - 0.5f;
            float fl = floorf(pp);
            float f = pp - fl;
            int i0 = (int)fl;
            iy[dy][0] = i0 < 0 ? 0 : i0;
            iy[dy][1] = (i0 + 1 > 15) ? 15 : (i0 + 1);
            wy[dy][0] = 1.f - f;
            wy[dy][1] = f;
        }
    }
    float acc = 0.f;
    for (int oc = 0; oc < 256; ++oc) {
        const float* sl = &Sl[oc * 48];
        float sv = 0.f;
        #pragma unroll
        for (int dy = 0; dy < 3; ++dy)
            sv += wy[dy][0] * sl[dy * 16 + iy[dy][0]] + wy[dy][1] * sl[dy * 16 + iy[dy][1]];
        sv += b1[oc];
        acc += fmaxf(sv, 0.f) * w2[oc];
    }
    out[(size_t)b * 65536 + y * 256 + x] = acc + b2p[0];
}

extern "C" void kernel_launch(void* const* d_in, const int* in_sizes, int n_in,
                              void* d_out, int out_size, void* d_ws, size_t ws_size,
                              hipStream_t stream)
{
    const float* x         = (const float*)d_in[0];
    const float* patch_w   = (const float*)d_in[1];
    const float* patch_b   = (const float*)d_in[2];
    const float* pos_embed = (const float*)d_in[3];
    const float* in_proj_w = (const float*)d_in[4];
    const float* in_proj_b = (const float*)d_in[5];
    const float* out_w     = (const float*)d_in[6];
    const float* out_b     = (const float*)d_in[7];
    const float* ln1_g     = (const float*)d_in[8];
    const float* ln1_b     = (const float*)d_in[9];
    const float* ln2_g     = (const float*)d_in[10];
    const float* ln2_b     = (const float*)d_in[11];
    const float* ffn_w1    = (const float*)d_in[12];
    const float* ffn_b1    = (const float*)d_in[13];
    const float* ffn_w2    = (const float*)d_in[14];
    const float* ffn_b2    = (const float*)d_in[15];
    const float* edge_w    = (const float*)d_in[16];
    const float* edge_b    = (const float*)d_in[17];
    const float* conv1_w   = (const float*)d_in[18];
    const float* conv1_b   = (const float*)d_in[19];
    const float* conv2_w   = (const float*)d_in[20];
    const float* conv2_b   = (const float*)d_in[21];
    float* out = (float*)d_out;
    float* ws = (float*)d_ws;

    float* patches = ws;                    // 393216
    float* h       = patches + 393216;      // 393216
    float* xl      = h + 393216;            // 393216
    float* qkv     = xl + 393216;           // 1179648
    float* orow    = qkv + 1179648;         // 393216
    float* ocol    = orow + 393216;         // 393216
    float* hid     = ocol + 393216;         // 1048576
    float* am      = hid + 1048576;         // 1024
    float* divacc  = am + 1024;             // 512
    float* hfin    = divacc + 512;          // 393216
    float* Wct     = hfin + 393216;         // 1769472
    float* Pb      = Wct + 1769472;         // 1179648
    float* Sb      = Pb + 1179648;          // 6291456

    hipMemsetAsync(divacc, 0, 512 * sizeof(float), stream);

    im2col_kernel<<<dim3(1536), 256, 0, stream>>>(x, patches);
    gemm_nt<MB | MPOS><<<dim3(12, 8, 1), 256, 0, stream>>>(
        patches, nullptr, patch_w, patch_b, pos_embed, h, 512, 768, 768, 1, 0, 0, 0, 0);
    wct_kernel<<<dim3(6912), 256, 0, stream>>>(conv1_w, Wct);

    for (int l = 0; l < NL; ++l) {
        ln_kernel<<<512, 256, 0, stream>>>(h, ln1_g + l * DIM, ln1_b + l * DIM, xl);
        gemm_nt<MB><<<dim3(36, 8, 1), 256, 0, stream>>>(
            xl, nullptr, in_proj_w + (size_t)l * 3 * DIM * DIM, in_proj_b + (size_t)l * 3 * DIM,
            nullptr, qkv, 512, 2304, 768, 1, 0, 0, 0, 0);
        attn_kernel<<<dim3(BB * GG, 2), 256, 0, stream>>>(qkv, orow, ocol, am);
        div_kernel<<<dim3(2), 256, 0, stream>>>(am, divacc);
        gemm_nt<MB2 | MSUM2 | MRES><<<dim3(12, 8, 1), 256, 0, stream>>>(
            orow, ocol, out_w + (size_t)l * DIM * DIM, out_b + (size_t)l * DIM,
            nullptr, h, 512, 768, 768, 1, 0, 0, 0, 0);
        ln_kernel<<<512, 256, 0, stream>>>(h, ln2_g + l * DIM, ln2_b + l * DIM, xl);
        gemm_nt<MB | MRELU><<<dim3(32, 8, 1), 256, 0, stream>>>(
            xl, nullptr, ffn_w1 + (size_t)l * FFD * DIM, ffn_b1 + (size_t)l * FFD,
            nullptr, hid, 512, 2048, 768, 1, 0, 0, 0, 0);
        gemm_nt<MB | MRES><<<dim3(12, 8, 1), 256, 0, stream>>>(
            hid, nullptr, ffn_w2 + (size_t)l * DIM * FFD, ffn_b2 + (size_t)l * DIM,
            nullptr, h, 512, 768, 2048, 1, 0, 0, 0, 0);
    }

    hfin_kernel<<<dim3(1536), 256, 0, stream>>>(h, divacc, edge_w, edge_b, hfin);
    // P[b][dy][dx][oc][pix] via batched gemm: z = dydx*2 + b
    gemm_nt<0><<<dim3(4, 4, 18), 256, 0, stream>>>(
        Wct, nullptr, hfin, nullptr, nullptr, Pb, 256, 256, 768,
        2, (long long)256 * 768, (long long)256 * 768, 65536LL, 9LL * 65536);
    s_kernel<<<dim3(24576), 256, 0, stream>>>(Pb, Sb);
    out_kernel<<<dim3(512), 256, 0, stream>>>(Sb, conv1_b, conv2_w, conv2_b, out);
}

// Round 2
// 757.170 us; speedup vs baseline: 3.2006x; 3.2006x over previous
//
#include <hip/hip_runtime.h>
#include <math.h>

#define BB 2
#define CIN 3
#define IMGS 256
#define PS 16
#define GG 16
#define NN 256
#define DIM 768
#define NH 12
#define NL 8
#define FFD 2048
#define LNEPS 1e-5f

typedef __attribute__((ext_vector_type(8))) short bf16x8;
typedef __attribute__((ext_vector_type(4))) float f32x4;

// ---- gemm mode flags ----
#define MB     1   // add bias[col]
#define MB2    2   // bias * 2 (implies bias)
#define MPOS   4   // add pos_embed[(row%256)*N + col]
#define MRELU  8
#define MRES   16  // C += result (residual, fp32)
#define MOBF16 32  // write bf16 to C16 instead of fp32 C

__device__ inline unsigned short b16(float f) {
    unsigned int u = __builtin_bit_cast(unsigned int, f);
    u += 0x7fffu + ((u >> 16) & 1u);   // RNE
    return (unsigned short)(u >> 16);
}

__device__ inline void gload16(const unsigned short* g, unsigned short* l) {
    __builtin_amdgcn_global_load_lds((const __attribute__((address_space(1))) void*)g,
                                     (__attribute__((address_space(3))) void*)l, 16, 0, 0);
}

// C[M,N] = A[M,K] (bf16) * B[N,K]^T (bf16) + epilogue. M,N %64==0, K %64==0.
// LDS: linear dest for global_load_lds; XOR swizzle (kc ^= row&7, 16B chunks)
// applied on the GLOBAL source and on the ds_read side (both-sides, rule #21).
template<int MODE>
__global__ __launch_bounds__(256) void gemm_bf16(
    const unsigned short* __restrict__ A, const unsigned short* __restrict__ B,
    const float* __restrict__ bias, const float* __restrict__ pos,
    float* __restrict__ C, unsigned short* __restrict__ C16,
    int M, int N, int K, int zdiv,
    long long sAo, long long sBi, long long sCo, long long sCi)
{
    int z = blockIdx.z;
    int zo = z / zdiv, zi = z % zdiv;
    A += (size_t)zo * sAo;
    B += (size_t)zi * sBi;
    long long coff = (long long)zo * sCo + (long long)zi * sCi;

    __shared__ unsigned short As[2][4096], Bs[2][4096];
    int tid = threadIdx.x;
    int lane = tid & 63, wave = tid >> 6;
    int wr = wave >> 1, wc = wave & 1;        // wave -> 32x32 quadrant
    int bm = blockIdx.y * 64, bn = blockIdx.x * 64;

    f32x4 acc[2][2] = {};

    auto stage = [&](int buf, int k0) {
        #pragma unroll
        for (int i = 0; i < 2; ++i) {
            int s = (wave * 2 + i) * 64 + lane;     // 16B slot, linear LDS
            int row = s >> 3;
            int kcl = (s & 7) ^ (row & 7);          // inverse-swizzled source
            gload16(A + (size_t)(bm + row) * K + k0 + kcl * 8, &As[buf][s * 8]);
        }
        #pragma unroll
        for (int i = 0; i < 2; ++i) {
            int s = (wave * 2 + i) * 64 + lane;
            int row = s >> 3;
            int kcl = (s & 7) ^ (row & 7);
            gload16(B + (size_t)(bn + row) * K + k0 + kcl * 8, &Bs[buf][s * 8]);
        }
    };

    int nt = K >> 6;
    stage(0, 0);
    __syncthreads();             // compiler emits vmcnt(0) drain before barrier
    int buf = 0;
    int rl = lane & 15, kh = lane >> 4;
    for (int t = 0; t < nt; ++t) {
        if (t + 1 < nt) stage(buf ^ 1, (t + 1) * 64);
        const unsigned short* Ab = As[buf];
        const unsigned short* Bb = Bs[buf];
        #pragma unroll
        for (int ks = 0; ks < 2; ++ks) {
            bf16x8 af[2], bf[2];
            int kc = ks * 4 + kh;
            #pragma unroll
            for (int mi = 0; mi < 2; ++mi) {
                int row = 32 * wr + 16 * mi + rl;
                af[mi] = *(const bf16x8*)(Ab + row * 64 + (kc ^ (row & 7)) * 8);
            }
            #pragma unroll
            for (int ni = 0; ni < 2; ++ni) {
                int row = 32 * wc + 16 * ni + rl;
                bf[ni] = *(const bf16x8*)(Bb + row * 64 + (kc ^ (row & 7)) * 8);
            }
            #pragma unroll
            for (int mi = 0; mi < 2; ++mi)
                #pragma unroll
                for (int ni = 0; ni < 2; ++ni)
                    acc[mi][ni] = __builtin_amdgcn_mfma_f32_16x16x32_bf16(
                        af[mi], bf[ni], acc[mi][ni], 0, 0, 0);
        }
        __syncthreads();
        buf ^= 1;
    }

    #pragma unroll
    for (int mi = 0; mi < 2; ++mi) {
        #pragma unroll
        for (int ni = 0; ni < 2; ++ni) {
            #pragma unroll
            for (int r = 0; r < 4; ++r) {
                int row = bm + 32 * wr + 16 * mi + (lane >> 4) * 4 + r;
                int col = bn + 32 * wc + 16 * ni + (lane & 15);
                float v = acc[mi][ni][r];
                if (MODE & (MB | MB2)) v += bias[col] * ((MODE & MB2) ? 2.f : 1.f);
                if (MODE & MPOS) v += pos[(size_t)(row & (NN - 1)) * N + col];
                if (MODE & MRELU) v = fmaxf(v, 0.f);
                long long ci = coff + (long long)row * N + col;
                if (MODE & MOBF16) C16[ci] = b16(v);
                else if (MODE & MRES) C[ci] += v;
                else C[ci] = v;
            }
        }
    }
}

// patches16[b*256+n][k] = bf16(x[b][c][gy*16+py][gx*16+px])
__global__ void im2col_kernel(const float* __restrict__ x, unsigned short* __restrict__ p16)
{
    int idx = blockIdx.x * 256 + threadIdx.x;   // < 393216
    int k = idx % DIM;
    int m = idx / DIM;
    int b = m >> 8, n = m & 255;
    int gy = n >> 4, gx = n & 15;
    int c = k >> 8, rem = k & 255, py = rem >> 4, px = rem & 15;
    p16[idx] = b16(x[((size_t)(b * CIN + c) * IMGS + gy * PS + py) * IMGS + gx * PS + px]);
}

// Wct16[dydx][oc][c] = bf16(conv1_w[oc][c][dy][dx])
__global__ void wct_kernel(const float* __restrict__ w, unsigned short* __restrict__ Wct)
{
    int idx = blockIdx.x * 256 + threadIdx.x;   // < 1769472
    int c = idx % DIM;
    int t = idx / DIM;
    int oc = t & 255;
    int dydx = t >> 8;
    int dy = dydx / 3, dx = dydx % 3;
    Wct[idx] = b16(w[((size_t)(oc * DIM + c) * 3 + dy) * 3 + dx]);
}

// generic fp32 -> bf16 (n % 4 == 0)
__global__ void cvt_kernel(const float* __restrict__ src, unsigned short* __restrict__ dst, int n)
{
    int i = (blockIdx.x * 256 + threadIdx.x) * 4;
    if (i >= n) return;
    float4 v = *(const float4*)(src + i);
    dst[i + 0] = b16(v.x); dst[i + 1] = b16(v.y);
    dst[i + 2] = b16(v.z); dst[i + 3] = b16(v.w);
}

// per-layer weight pack: [ipw 1769472][outw 589824][ffn1 1572864][ffn2 1572864]
#define LW_IPW  0
#define LW_OUTW 1769472
#define LW_FW1  2359296
#define LW_FW2  3932160
#define LW_TOT  5505024
__global__ void cvt_layer_kernel(const float* __restrict__ ipw, const float* __restrict__ ow,
                                 const float* __restrict__ f1, const float* __restrict__ f2,
                                 unsigned short* __restrict__ dst)
{
    int i = (blockIdx.x * 256 + threadIdx.x) * 4;   // < LW_TOT
    if (i >= LW_TOT) return;
    const float* src; int off;
    if (i < LW_OUTW)      { src = ipw; off = i; }
    else if (i < LW_FW1)  { src = ow;  off = i - LW_OUTW; }
    else if (i < LW_FW2)  { src = f1;  off = i - LW_FW1; }
    else                  { src = f2;  off = i - LW_FW2; }
    float4 v = *(const float4*)(src + off);
    dst[i + 0] = b16(v.x); dst[i + 1] = b16(v.y);
    dst[i + 2] = b16(v.z); dst[i + 3] = b16(v.w);
}

__global__ __launch_bounds__(256) void ln_kernel(
    const float* __restrict__ X, const float* __restrict__ g,
    const float* __restrict__ bta, unsigned short* __restrict__ Y)
{
    int row = blockIdx.x;
    int tid = threadIdx.x;
    const float* xp = X + (size_t)row * DIM;
    float v0 = xp[tid], v1 = xp[tid + 256], v2 = xp[tid + 512];
    float s = v0 + v1 + v2, s2 = v0 * v0 + v1 * v1 + v2 * v2;
    #pragma unroll
    for (int off = 32; off > 0; off >>= 1) {
        s  += __shfl_down(s, off);
        s2 += __shfl_down(s2, off);
    }
    __shared__ float r1[4], r2[4], mstat[2];
    if ((tid & 63) == 0) { r1[tid >> 6] = s; r2[tid >> 6] = s2; }
    __syncthreads();
    if (tid == 0) {
        float a = r1[0] + r1[1] + r1[2] + r1[3];
        float c = r2[0] + r2[1] + r2[2] + r2[3];
        float mean = a * (1.f / DIM);
        float var = c * (1.f / DIM) - mean * mean;
        mstat[0] = mean;
        mstat[1] = 1.f / sqrtf(var + LNEPS);
    }
    __syncthreads();
    float mean = mstat[0], inv = mstat[1];
    unsigned short* yp = Y + (size_t)row * DIM;
    yp[tid]       = b16((v0 - mean) * inv * g[tid]       + bta[tid]);
    yp[tid + 256] = b16((v1 - mean) * inv * g[tid + 256] + bta[tid + 256]);
    yp[tid + 512] = b16((v2 - mean) * inv * g[tid + 512] + bta[tid + 512]);
}

// grid (B*G, 2 types, 12 heads). fp32 math on fp32 qkv.
__global__ __launch_bounds__(256) void attn_kernel(
    const float* __restrict__ qkv, float* __restrict__ orow,
    float* __restrict__ ocol, float* __restrict__ amh)
{
    int b = blockIdx.x >> 4, g = blockIdx.x & 15;
    int type = blockIdx.y;
    int hh = blockIdx.z;
    int tid = threadIdx.x;
    __shared__ float qs[16][68], ks[16][68], vs[16][68], as_[16][17];
    #pragma unroll
    for (int l = 0; l < 4; ++l) {
        int e = tid + l * 256;
        int s = e >> 6, d = e & 63;
        int n = (type == 0) ? (s * GG + g) : (g * GG + s);
        const float* base = qkv + (size_t)(b * NN + n) * (3 * DIM) + hh * 64 + d;
        qs[s][d] = base[0];
        ks[s][d] = base[DIM];
        vs[s][d] = base[2 * DIM];
    }
    __syncthreads();
    int s = tid >> 4, t = tid & 15;
    float sc = 0.f;
    #pragma unroll
    for (int d = 0; d < 64; ++d) sc += qs[s][d] * ks[t][d];
    sc *= 0.125f;
    float mx = sc;
    #pragma unroll
    for (int off = 1; off < 16; off <<= 1) mx = fmaxf(mx, __shfl_xor(mx, off, 16));
    float p = __expf(sc - mx);
    float sum = p;
    #pragma unroll
    for (int off = 1; off < 16; off <<= 1) sum += __shfl_xor(sum, off, 16);
    as_[s][t] = p / sum;
    __syncthreads();
    if (tid < 16) {
        float a = 0.f;
        #pragma unroll
        for (int ss = 0; ss < 16; ++ss) a += as_[ss][tid];
        amh[(((size_t)(type * BB + b) * GG + g) * GG + tid) * NH + hh] = a;
    }
    int s2 = tid >> 4, dg = (tid & 15) * 4;
    float o0 = 0, o1 = 0, o2 = 0, o3 = 0;
    #pragma unroll
    for (int t2 = 0; t2 < 16; ++t2) {
        float a2 = as_[s2][t2];
        o0 += a2 * vs[t2][dg];
        o1 += a2 * vs[t2][dg + 1];
        o2 += a2 * vs[t2][dg + 2];
        o3 += a2 * vs[t2][dg + 3];
    }
    int n2 = (type == 0) ? (s2 * GG + g) : (g * GG + s2);
    float* op = ((type == 0) ? orow : ocol) + (size_t)(b * NN + n2) * DIM + hh * 64 + dg;
    op[0] = o0; op[1] = o1; op[2] = o2; op[3] = o3;
}

__global__ void div_kernel(const float* __restrict__ amh, float* __restrict__ divacc)
{
    int i = blockIdx.x * 256 + threadIdx.x;     // < 512
    int bq = i >> 8, n = i & 255;
    int g = n >> 4, t = n & 15;
    float rs = 0.f, cs = 0.f;
    #pragma unroll
    for (int h = 0; h < NH; ++h) {
        rs += amh[(((size_t)(0 * BB + bq) * GG + g) * GG + t) * NH + h];
        cs += amh[(((size_t)(1 * BB + bq) * GG + g) * GG + t) * NH + h];
    }
    divacc[i] += fabsf(rs - cs) * (1.f / (NH * GG));
}

__global__ void osum_kernel(const float* __restrict__ orow, const float* __restrict__ ocol,
                            unsigned short* __restrict__ o16)
{
    int i = (blockIdx.x * 256 + threadIdx.x) * 4;   // < 393216
    float4 a = *(const float4*)(orow + i);
    float4 c = *(const float4*)(ocol + i);
    o16[i + 0] = b16(a.x + c.x); o16[i + 1] = b16(a.y + c.y);
    o16[i + 2] = b16(a.z + c.z); o16[i + 3] = b16(a.w + c.w);
}

// hfin16 = bf16(h + (divacc/L)*edge_w + edge_b)
__global__ void hfin_kernel(const float* __restrict__ h, const float* __restrict__ divacc,
                            const float* __restrict__ ew, const float* __restrict__ eb,
                            unsigned short* __restrict__ hf)
{
    int idx = blockIdx.x * 256 + threadIdx.x;   // < 393216
    int d = idx % DIM, m = idx / DIM;
    hf[idx] = b16(h[idx] + divacc[m] * (1.f / NL) * ew[d] + eb[d]);
}

// S[b][x][oc][dy][i] = sum over dx,j of ax(x+dx-1, j) * P[b][dy][dx][oc][i*16+j]
__global__ void s_kernel(const float* __restrict__ P, float* __restrict__ S)
{
    int idx = blockIdx.x * 256 + threadIdx.x;   // < 2*256*256*48
    int i = idx & 15;
    int dy = (idx >> 4) % 3;
    int t = idx / 48;
    int oc = t & 255;
    int x = (t >> 8) & 255;
    int b = t >> 16;
    float acc = 0.f;
    #pragma unroll
    for (int dx = 0; dx < 3; ++dx) {
        int u = x + dx - 1;
        if (u < 0 || u > 255) continue;
        float p = (u + 0.5f) * 0.0625f - 0.5f;
        float fl = floorf(p);
        float f = p - fl;
        int j0 = (int)fl;
        int ja = j0 < 0 ? 0 : j0;
        int jb = (j0 + 1 > 15) ? 15 : (j0 + 1);
        const float* Pp = P + ((((size_t)(b * 3 + dy) * 3 + dx) * 256 + oc) << 8) + (i << 4);
        acc += (1.f - f) * Pp[ja] + f * Pp[jb];
    }
    S[idx] = acc;
}

__global__ __launch_bounds__(256) void out_kernel(
    const float* __restrict__ S, const float* __restrict__ b1,
    const float* __restrict__ w2, const float* __restrict__ b2p,
    float* __restrict__ out)
{
    int b = blockIdx.x >> 8, x = blockIdx.x & 255;
    __shared__ float Sl[12288];
    const float* Sp = S + (size_t)(b * 256 + x) * 12288;
    for (int l = threadIdx.x; l < 12288; l += 256) Sl[l] = Sp[l];
    __syncthreads();
    int y = threadIdx.x;
    float wy[3][2];
    int iy[3][2];
    #pragma unroll
    for (int dy = 0; dy < 3; ++dy) {
        int v = y + dy - 1;
        if (v < 0 || v > 255) {
            wy[dy][0] = wy[dy][1] = 0.f;
            iy[dy][0] = iy[dy][1] = 0;
        } else {
            float pp = (v + 0.5f) * 0.0625f - 0.5f;
            float fl = floorf(pp);
            float f = pp - fl;
            int i0 = (int)fl;
            iy[dy][0] = i0 < 0 ? 0 : i0;
            iy[dy][1] = (i0 + 1 > 15) ? 15 : (i0 + 1);
            wy[dy][0] = 1.f - f;
            wy[dy][1] = f;
        }
    }
    float acc = 0.f;
    for (int oc = 0; oc < 256; ++oc) {
        const float* sl = &Sl[oc * 48];
        float sv = 0.f;
        #pragma unroll
        for (int dy = 0; dy < 3; ++dy)
            sv += wy[dy][0] * sl[dy * 16 + iy[dy][0]] + wy[dy][1] * sl[dy * 16 + iy[dy][1]];
        sv += b1[oc];
        acc += fmaxf(sv, 0.f) * w2[oc];
    }
    out[(size_t)b * 65536 + y * 256 + x] = acc + b2p[0];
}

extern "C" void kernel_launch(void* const* d_in, const int* in_sizes, int n_in,
                              void* d_out, int out_size, void* d_ws, size_t ws_size,
                              hipStream_t stream)
{
    const float* x         = (const float*)d_in[0];
    const float* patch_w   = (const float*)d_in[1];
    const float* patch_b   = (const float*)d_in[2];
    const float* pos_embed = (const float*)d_in[3];
    const float* in_proj_w = (const float*)d_in[4];
    const float* in_proj_b = (const float*)d_in[5];
    const float* out_w     = (const float*)d_in[6];
    const float* out_b     = (const float*)d_in[7];
    const float* ln1_g     = (const float*)d_in[8];
    const float* ln1_b     = (const float*)d_in[9];
    const float* ln2_g     = (const float*)d_in[10];
    const float* ln2_b     = (const float*)d_in[11];
    const float* ffn_w1    = (const float*)d_in[12];
    const float* ffn_b1    = (const float*)d_in[13];
    const float* ffn_w2    = (const float*)d_in[14];
    const float* ffn_b2    = (const float*)d_in[15];
    const float* edge_w    = (const float*)d_in[16];
    const float* edge_b    = (const float*)d_in[17];
    const float* conv1_w   = (const float*)d_in[18];
    const float* conv1_b   = (const float*)d_in[19];
    const float* conv2_w   = (const float*)d_in[20];
    const float* conv2_b   = (const float*)d_in[21];
    float* out = (float*)d_out;
    float* ws = (float*)d_ws;

    float* h      = ws;                        // 393216
    float* qkv    = h + 393216;                // 1179648
    float* orow   = qkv + 1179648;             // 393216
    float* ocol   = orow + 393216;             // 393216
    float* Pb     = ocol + 393216;             // 1179648
    float* Sb     = Pb + 1179648;              // 6291456
    float* amh    = Sb + 6291456;              // 12288
    float* divacc = amh + 12288;               // 512
    unsigned short* patches16 = (unsigned short*)(divacc + 512);   // 393216
    unsigned short* xl16   = patches16 + 393216;                   // 393216
    unsigned short* osum16 = xl16 + 393216;                        // 393216
    unsigned short* hid16  = osum16 + 393216;                      // 1048576
    unsigned short* hfin16 = hid16 + 1048576;                      // 393216
    unsigned short* Wct16  = hfin16 + 393216;                      // 1769472
    unsigned short* pw16   = Wct16 + 1769472;                      // 589824
    unsigned short* lw16   = pw16 + 589824;                        // 5505024

    hipMemsetAsync(divacc, 0, 512 * sizeof(float), stream);

    im2col_kernel<<<dim3(1536), 256, 0, stream>>>(x, patches16);
    cvt_kernel<<<dim3(576), 256, 0, stream>>>(patch_w, pw16, 589824);
    wct_kernel<<<dim3(6912), 256, 0, stream>>>(conv1_w, Wct16);
    gemm_bf16<MB | MPOS><<<dim3(12, 8, 1), 256, 0, stream>>>(
        patches16, pw16, patch_b, pos_embed, h, nullptr, 512, 768, 768, 1, 0, 0, 0, 0);

    for (int l = 0; l < NL; ++l) {
        cvt_layer_kernel<<<dim3(5376), 256, 0, stream>>>(
            in_proj_w + (size_t)l * 1769472, out_w + (size_t)l * 589824,
            ffn_w1 + (size_t)l * 1572864, ffn_w2 + (size_t)l * 1572864, lw16);
        ln_kernel<<<512, 256, 0, stream>>>(h, ln1_g + l * DIM, ln1_b + l * DIM, xl16);
        gemm_bf16<MB><<<dim3(36, 8, 1), 256, 0, stream>>>(
            xl16, lw16 + LW_IPW, in_proj_b + (size_t)l * 3 * DIM, nullptr,
            qkv, nullptr, 512, 2304, 768, 1, 0, 0, 0, 0);
        attn_kernel<<<dim3(BB * GG, 2, NH), 256, 0, stream>>>(qkv, orow, ocol, amh);
        div_kernel<<<dim3(2), 256, 0, stream>>>(amh, divacc);
        osum_kernel<<<dim3(384), 256, 0, stream>>>(orow, ocol, osum16);
        gemm_bf16<MB2 | MRES><<<dim3(12, 8, 1), 256, 0, stream>>>(
            osum16, lw16 + LW_OUTW, out_b + (size_t)l * DIM, nullptr,
            h, nullptr, 512, 768, 768, 1, 0, 0, 0, 0);
        ln_kernel<<<512, 256, 0, stream>>>(h, ln2_g + l * DIM, ln2_b + l * DIM, xl16);
        gemm_bf16<MB | MRELU | MOBF16><<<dim3(32, 8, 1), 256, 0, stream>>>(
            xl16, lw16 + LW_FW1, ffn_b1 + (size_t)l * FFD, nullptr,
            nullptr, hid16, 512, 2048, 768, 1, 0, 0, 0, 0);
        gemm_bf16<MB | MRES><<<dim3(12, 8, 1), 256, 0, stream>>>(
            hid16, lw16 + LW_FW2, ffn_b2 + (size_t)l * DIM, nullptr,
            h, nullptr, 512, 768, 2048, 1, 0, 0, 0, 0);
    }

    hfin_kernel<<<dim3(1536), 256, 0, stream>>>(h, divacc, edge_w, edge_b, hfin16);
    // P[b][dy][dx][oc][pix]: z = dydx*2 + b
    gemm_bf16<0><<<dim3(4, 4, 18), 256, 0, stream>>>(
        Wct16, hfin16, nullptr, nullptr, Pb, nullptr, 256, 256, 768,
        2, (long long)256 * 768, (long long)256 * 768, 65536LL, 9LL * 65536);
    s_kernel<<<dim3(24576), 256, 0, stream>>>(Pb, Sb);
    out_kernel<<<dim3(512), 256, 0, stream>>>(Sb, conv1_b, conv2_w, conv2_b, out);
}

// Round 3
// 714.022 us; speedup vs baseline: 3.3940x; 1.0604x over previous
//
#include <hip/hip_runtime.h>
#include <hip/hip_bf16.h>
#include <math.h>

#define BB 2
#define CIN 3
#define IMGS 256
#define PS 16
#define GG 16
#define NN 256
#define DIM 768
#define NH 12
#define NL 8
#define FFD 2048
#define LNEPS 1e-5f

typedef __attribute__((ext_vector_type(8))) short bf16x8;
typedef __attribute__((ext_vector_type(4))) float f32x4;

// ---- gemm mode flags ----
#define MB     1    // add bias[col]
#define MB2    2    // bias * 2 (implies bias)
#define MPOS   4    // add pos_embed[(row%256)*N + col]
#define MRELU  8
#define MRES   16   // C += result (residual, fp32)
#define MOBF16 32   // write bf16 to C16 instead of fp32 C
#define MAS2   64   // A = two fp32 arrays, summed + converted during staging
#define MBF32  128  // B = fp32 array, converted during staging

__device__ inline unsigned short bc(float f) {
    return __builtin_bit_cast(unsigned short, __float2bfloat16(f));
}

__device__ inline void gload16(const unsigned short* g, unsigned short* l) {
    __builtin_amdgcn_global_load_lds((const __attribute__((address_space(1))) void*)g,
                                     (__attribute__((address_space(3))) void*)l, 16, 0, 0);
}

// C[M,N] = A[M,K] * B[N,K]^T + epilogue. M,N %64==0, K %64==0.
// LDS: linear dest; XOR swizzle (kc ^= row&7, 16B chunks) applied on the
// source index and on the ds_read side (both-sides, rule #21).
template<int MODE>
__global__ __launch_bounds__(256) void gemm_bf16(
    const void* __restrict__ Av, const void* __restrict__ A2v, const void* __restrict__ Bv,
    const float* __restrict__ bias, const float* __restrict__ pos,
    float* __restrict__ C, unsigned short* __restrict__ C16,
    int M, int N, int K, int zdiv,
    long long sAo, long long sBi, long long sCo, long long sCi)
{
    int z = blockIdx.z;
    int zo = z / zdiv, zi = z % zdiv;
    const unsigned short* A16 = (const unsigned short*)Av + (size_t)zo * sAo;
    const float* Af  = (const float*)Av  + (size_t)zo * sAo;
    const float* Af2 = (const float*)A2v + (size_t)zo * sAo;
    const unsigned short* B16 = (const unsigned short*)Bv + (size_t)zi * sBi;
    const float* Bf  = (const float*)Bv  + (size_t)zi * sBi;
    long long coff = (long long)zo * sCo + (long long)zi * sCi;

    __shared__ unsigned short As[2][4096], Bs[2][4096];
    int tid = threadIdx.x;
    int lane = tid & 63, wave = tid >> 6;
    int wr = wave >> 1, wc = wave & 1;        // wave -> 32x32 quadrant
    int bm = blockIdx.y * 64, bn = blockIdx.x * 64;

    f32x4 acc[2][2] = {};
    f32x4 rA[2][2], rA2[2][2], rB[2][2];

    auto gstageA = [&](int b, int kt) {
        #pragma unroll
        for (int i = 0; i < 2; ++i) {
            int s = (wave * 2 + i) * 64 + lane;
            int row = s >> 3, kcl = (s & 7) ^ (row & 7);
            gload16(A16 + (size_t)(bm + row) * K + kt * 64 + kcl * 8, &As[b][s * 8]);
        }
    };
    auto gstageB = [&](int b, int kt) {
        #pragma unroll
        for (int i = 0; i < 2; ++i) {
            int s = (wave * 2 + i) * 64 + lane;
            int row = s >> 3, kcl = (s & 7) ^ (row & 7);
            gload16(B16 + (size_t)(bn + row) * K + kt * 64 + kcl * 8, &Bs[b][s * 8]);
        }
    };
    auto ldA = [&](int kt) {
        #pragma unroll
        for (int i = 0; i < 2; ++i) {
            int s = (wave * 2 + i) * 64 + lane;
            int row = s >> 3, kcl = (s & 7) ^ (row & 7);
            size_t off = (size_t)(bm + row) * K + kt * 64 + kcl * 8;
            rA[i][0]  = *(const f32x4*)(Af + off);
            rA[i][1]  = *(const f32x4*)(Af + off + 4);
            rA2[i][0] = *(const f32x4*)(Af2 + off);
            rA2[i][1] = *(const f32x4*)(Af2 + off + 4);
        }
    };
    auto ldB = [&](int kt) {
        #pragma unroll
        for (int i = 0; i < 2; ++i) {
            int s = (wave * 2 + i) * 64 + lane;
            int row = s >> 3, kcl = (s & 7) ^ (row & 7);
            size_t off = (size_t)(bn + row) * K + kt * 64 + kcl * 8;
            rB[i][0] = *(const f32x4*)(Bf + off);
            rB[i][1] = *(const f32x4*)(Bf + off + 4);
        }
    };
    auto wrA = [&](int b) {
        #pragma unroll
        for (int i = 0; i < 2; ++i) {
            int s = (wave * 2 + i) * 64 + lane;
            bf16x8 v;
            #pragma unroll
            for (int j = 0; j < 4; ++j) {
                v[j]     = (short)bc(rA[i][0][j] + rA2[i][0][j]);
                v[4 + j] = (short)bc(rA[i][1][j] + rA2[i][1][j]);
            }
            *(bf16x8*)(&As[b][s * 8]) = v;
        }
    };
    auto wrB = [&](int b) {
        #pragma unroll
        for (int i = 0; i < 2; ++i) {
            int s = (wave * 2 + i) * 64 + lane;
            bf16x8 v;
            #pragma unroll
            for (int j = 0; j < 4; ++j) {
                v[j]     = (short)bc(rB[i][0][j]);
                v[4 + j] = (short)bc(rB[i][1][j]);
            }
            *(bf16x8*)(&Bs[b][s * 8]) = v;
        }
    };
    auto compute = [&](int b) {
        const unsigned short* Ab = As[b];
        const unsigned short* Bb = Bs[b];
        int rl = lane & 15, kh = lane >> 4;
        #pragma unroll
        for (int ks = 0; ks < 2; ++ks) {
            bf16x8 af[2], bfr[2];
            int kc = ks * 4 + kh;
            #pragma unroll
            for (int mi = 0; mi < 2; ++mi) {
                int row = 32 * wr + 16 * mi + rl;
                af[mi] = *(const bf16x8*)(Ab + row * 64 + (kc ^ (row & 7)) * 8);
            }
            #pragma unroll
            for (int ni = 0; ni < 2; ++ni) {
                int row = 32 * wc + 16 * ni + rl;
                bfr[ni] = *(const bf16x8*)(Bb + row * 64 + (kc ^ (row & 7)) * 8);
            }
            #pragma unroll
            for (int mi = 0; mi < 2; ++mi)
                #pragma unroll
                for (int ni = 0; ni < 2; ++ni)
                    acc[mi][ni] = __builtin_amdgcn_mfma_f32_16x16x32_bf16(
                        af[mi], bfr[ni], acc[mi][ni], 0, 0, 0);
        }
    };

    int nt = K >> 6;
    if constexpr (!(MODE & MAS2)) gstageA(0, 0); else { ldA(0); wrA(0); }
    if constexpr (!(MODE & MBF32)) gstageB(0, 0); else { ldB(0); wrB(0); }
    __syncthreads();
    int buf = 0;
    for (int t = 0; t < nt; ++t) {
        if (t + 1 < nt) {
            if constexpr (!(MODE & MAS2)) gstageA(buf ^ 1, t + 1); else ldA(t + 1);
            if constexpr (!(MODE & MBF32)) gstageB(buf ^ 1, t + 1); else ldB(t + 1);
        }
        compute(buf);
        if (t + 1 < nt) {
            if constexpr (MODE & MAS2) wrA(buf ^ 1);
            if constexpr (MODE & MBF32) wrB(buf ^ 1);
        }
        __syncthreads();
        buf ^= 1;
    }

    #pragma unroll
    for (int mi = 0; mi < 2; ++mi) {
        #pragma unroll
        for (int ni = 0; ni < 2; ++ni) {
            #pragma unroll
            for (int r = 0; r < 4; ++r) {
                int row = bm + 32 * wr + 16 * mi + (lane >> 4) * 4 + r;
                int col = bn + 32 * wc + 16 * ni + (lane & 15);
                float v = acc[mi][ni][r];
                if (MODE & (MB | MB2)) v += bias[col] * ((MODE & MB2) ? 2.f : 1.f);
                if (MODE & MPOS) v += pos[(size_t)(row & (NN - 1)) * N + col];
                if (MODE & MRELU) v = fmaxf(v, 0.f);
                long long ci = coff + (long long)row * N + col;
                if (MODE & MOBF16) C16[ci] = bc(v);
                else if (MODE & MRES) C[ci] += v;
                else C[ci] = v;
            }
        }
    }
}

// patches16[b*256+n][k] = bf16(x[b][c][gy*16+py][gx*16+px])
__global__ void im2col_kernel(const float* __restrict__ x, unsigned short* __restrict__ p16)
{
    int idx = blockIdx.x * 256 + threadIdx.x;   // < 393216
    int k = idx % DIM;
    int m = idx / DIM;
    int b = m >> 8, n = m & 255;
    int gy = n >> 4, gx = n & 15;
    int c = k >> 8, rem = k & 255, py = rem >> 4, px = rem & 15;
    p16[idx] = bc(x[((size_t)(b * CIN + c) * IMGS + gy * PS + py) * IMGS + gx * PS + px]);
}

// Wct16[dydx][oc][c] = bf16(conv1_w[oc][c][dy][dx])
__global__ void wct_kernel(const float* __restrict__ w, unsigned short* __restrict__ Wct)
{
    int idx = blockIdx.x * 256 + threadIdx.x;   // < 1769472
    int c = idx % DIM;
    int t = idx / DIM;
    int oc = t & 255;
    int dydx = t >> 8;
    int dy = dydx / 3, dx = dydx % 3;
    Wct[idx] = bc(w[((size_t)(oc * DIM + c) * 3 + dy) * 3 + dx]);
}

__global__ __launch_bounds__(256) void ln_kernel(
    const float* __restrict__ X, const float* __restrict__ g,
    const float* __restrict__ bta, unsigned short* __restrict__ Y)
{
    int row = blockIdx.x;
    int tid = threadIdx.x;
    const float* xp = X + (size_t)row * DIM;
    float v0 = xp[tid], v1 = xp[tid + 256], v2 = xp[tid + 512];
    float s = v0 + v1 + v2, s2 = v0 * v0 + v1 * v1 + v2 * v2;
    #pragma unroll
    for (int off = 32; off > 0; off >>= 1) {
        s  += __shfl_down(s, off);
        s2 += __shfl_down(s2, off);
    }
    __shared__ float r1[4], r2[4], mstat[2];
    if ((tid & 63) == 0) { r1[tid >> 6] = s; r2[tid >> 6] = s2; }
    __syncthreads();
    if (tid == 0) {
        float a = r1[0] + r1[1] + r1[2] + r1[3];
        float c = r2[0] + r2[1] + r2[2] + r2[3];
        float mean = a * (1.f / DIM);
        float var = c * (1.f / DIM) - mean * mean;
        mstat[0] = mean;
        mstat[1] = 1.f / sqrtf(var + LNEPS);
    }
    __syncthreads();
    float mean = mstat[0], inv = mstat[1];
    unsigned short* yp = Y + (size_t)row * DIM;
    yp[tid]       = bc((v0 - mean) * inv * g[tid]       + bta[tid]);
    yp[tid + 256] = bc((v1 - mean) * inv * g[tid + 256] + bta[tid + 256]);
    yp[tid + 512] = bc((v2 - mean) * inv * g[tid + 512] + bta[tid + 512]);
}

// grid (B*G, 2 types, 12 heads). amh slice: [type][b][n][h] (per layer, 12288 floats)
__global__ __launch_bounds__(256) void attn_kernel(
    const float* __restrict__ qkv, float* __restrict__ orow,
    float* __restrict__ ocol, float* __restrict__ amh)
{
    int b = blockIdx.x >> 4, g = blockIdx.x & 15;
    int type = blockIdx.y;
    int hh = blockIdx.z;
    int tid = threadIdx.x;
    __shared__ float qs[16][68], ks[16][68], vs[16][68], as_[16][17];
    #pragma unroll
    for (int l = 0; l < 4; ++l) {
        int e = tid + l * 256;
        int s = e >> 6, d = e & 63;
        int n = (type == 0) ? (s * GG + g) : (g * GG + s);
        const float* base = qkv + (size_t)(b * NN + n) * (3 * DIM) + hh * 64 + d;
        qs[s][d] = base[0];
        ks[s][d] = base[DIM];
        vs[s][d] = base[2 * DIM];
    }
    __syncthreads();
    int s = tid >> 4, t = tid & 15;
    float sc = 0.f;
    #pragma unroll
    for (int d = 0; d < 64; ++d) sc += qs[s][d] * ks[t][d];
    sc *= 0.125f;
    float mx = sc;
    #pragma unroll
    for (int off = 1; off < 16; off <<= 1) mx = fmaxf(mx, __shfl_xor(mx, off, 16));
    float p = __expf(sc - mx);
    float sum = p;
    #pragma unroll
    for (int off = 1; off < 16; off <<= 1) sum += __shfl_xor(sum, off, 16);
    as_[s][t] = p / sum;
    __syncthreads();
    if (tid < 16) {
        float a = 0.f;
        #pragma unroll
        for (int ss = 0; ss < 16; ++ss) a += as_[ss][tid];
        amh[((size_t)(type * BB + b) * NN + g * GG + tid) * NH + hh] = a;
    }
    int s2 = tid >> 4, dg = (tid & 15) * 4;
    float o0 = 0, o1 = 0, o2 = 0, o3 = 0;
    #pragma unroll
    for (int t2 = 0; t2 < 16; ++t2) {
        float a2 = as_[s2][t2];
        o0 += a2 * vs[t2][dg];
        o1 += a2 * vs[t2][dg + 1];
        o2 += a2 * vs[t2][dg + 2];
        o3 += a2 * vs[t2][dg + 3];
    }
    int n2 = (type == 0) ? (s2 * GG + g) : (g * GG + s2);
    float* op = ((type == 0) ? orow : ocol) + (size_t)(b * NN + n2) * DIM + hh * 64 + dg;
    op[0] = o0; op[1] = o1; op[2] = o2; op[3] = o3;
}

// divacc[b*256+n] = sum_l |rowmean - colmean| / (NH*GG). amh: [L][2][B][256][12]
__global__ void divred_kernel(const float* __restrict__ amh, float* __restrict__ divacc)
{
    int i = blockIdx.x * 256 + threadIdx.x;     // < 512
    int b = i >> 8, n = i & 255;
    float acc = 0.f;
    #pragma unroll
    for (int l = 0; l < NL; ++l) {
        float rs = 0.f, cs = 0.f;
        const float* base = amh + (size_t)l * 12288 + (size_t)b * 3072 + n * 12;
        #pragma unroll
        for (int h = 0; h < NH; ++h) {
            rs += base[h];
            cs += base[6144 + h];
        }
        acc += fabsf(rs - cs);
    }
    divacc[i] = acc * (1.f / (NH * GG));
}

// hfin16 = bf16(h + (divacc/L)*edge_w + edge_b)
__global__ void hfin_kernel(const float* __restrict__ h, const float* __restrict__ divacc,
                            const float* __restrict__ ew, const float* __restrict__ eb,
                            unsigned short* __restrict__ hf)
{
    int idx = blockIdx.x * 256 + threadIdx.x;   // < 393216
    int d = idx % DIM, m = idx / DIM;
    hf[idx] = bc(h[idx] + divacc[m] * (1.f / NL) * ew[d] + eb[d]);
}

// S[b][x][dy][oc][i] = sum over dx,j of ax(x+dx-1, j) * P[b][dy*3+dx][oc][i*16+j]
// block: (ocg 0..63, b*3+dy). LDS holds P transposed [dx][oc4][j][i] (pad 17).
__global__ __launch_bounds__(256) void s_kernel(const float* __restrict__ P, float* __restrict__ S)
{
    int bdy = blockIdx.y;
    int b = bdy / 3, dy = bdy % 3;
    int ocg = blockIdx.x;
    __shared__ float Pl[3][4][16][17];
    int tid = threadIdx.x;
    #pragma unroll
    for (int l = 0; l < 12; ++l) {
        int e = l * 256 + tid;
        int dx = e >> 10, rem = e & 1023;
        int oc = rem >> 8, pix = rem & 255;
        int i = pix >> 4, j = pix & 15;
        Pl[dx][oc][j][i] =
            P[(((size_t)b * 9 + dy * 3 + dx) * 256 + ocg * 4 + oc) * 256 + pix];
    }
    __syncthreads();
    int xq = tid >> 6, oc = (tid >> 4) & 3, i = tid & 15;
    for (int xx = 0; xx < 64; ++xx) {
        int x = xq * 64 + xx;
        float acc = 0.f;
        #pragma unroll
        for (int dx = 0; dx < 3; ++dx) {
            int u = x + dx - 1;
            float p = (u + 0.5f) * 0.0625f - 0.5f;
            float fl = floorf(p);
            float f = p - fl;
            int j0 = (int)fl;
            int ja = j0 < 0 ? 0 : j0;
            int jb = (j0 + 1 > 15) ? 15 : (j0 + 1);
            bool valid = (u >= 0) && (u <= 255);
            float w0 = valid ? 1.f - f : 0.f;
            float w1 = valid ? f : 0.f;
            acc += w0 * Pl[dx][oc][ja][i] + w1 * Pl[dx][oc][jb][i];
        }
        S[(((size_t)(b * 256 + x) * 3 + dy) * 256 + ocg * 4 + oc) * 16 + i] = acc;
    }
}

// out[b][y][x]; S slab per (b,x): [dy][oc][i] = 3*256*16
__global__ __launch_bounds__(256) void out_kernel(
    const float* __restrict__ S, const float* __restrict__ b1,
    const float* __restrict__ w2, const float* __restrict__ b2p,
    float* __restrict__ out)
{
    int b = blockIdx.x >> 8, x = blockIdx.x & 255;
    __shared__ float Sl[12288];
    const float* Sp = S + (size_t)(b * 256 + x) * 12288;
    for (int l = threadIdx.x; l < 12288; l += 256) Sl[l] = Sp[l];
    __syncthreads();
    int y = threadIdx.x;
    float wy[3][2];
    int iy[3][2];
    #pragma unroll
    for (int dy = 0; dy < 3; ++dy) {
        int v = y + dy - 1;
        if (v < 0 || v > 255) {
            wy[dy][0] = wy[dy][1] = 0.f;
            iy[dy][0] = iy[dy][1] = 0;
        } else {
            float pp = (v + 0.5f) * 0.0625f - 0.5f;
            float fl = floorf(pp);
            float f = pp - fl;
            int i0 = (int)fl;
            iy[dy][0] = i0 < 0 ? 0 : i0;
            iy[dy][1] = (i0 + 1 > 15) ? 15 : (i0 + 1);
            wy[dy][0] = 1.f - f;
            wy[dy][1] = f;
        }
    }
    float acc = 0.f;
    for (int oc = 0; oc < 256; ++oc) {
        float sv = 0.f;
        #pragma unroll
        for (int dy = 0; dy < 3; ++dy)
            sv += wy[dy][0] * Sl[dy * 4096 + oc * 16 + iy[dy][0]]
                + wy[dy][1] * Sl[dy * 4096 + oc * 16 + iy[dy][1]];
        sv += b1[oc];
        acc += fmaxf(sv, 0.f) * w2[oc];
    }
    out[(size_t)b * 65536 + y * 256 + x] = acc + b2p[0];
}

extern "C" void kernel_launch(void* const* d_in, const int* in_sizes, int n_in,
                              void* d_out, int out_size, void* d_ws, size_t ws_size,
                              hipStream_t stream)
{
    const float* x         = (const float*)d_in[0];
    const float* patch_w   = (const float*)d_in[1];
    const float* patch_b   = (const float*)d_in[2];
    const float* pos_embed = (const float*)d_in[3];
    const float* in_proj_w = (const float*)d_in[4];
    const float* in_proj_b = (const float*)d_in[5];
    const float* out_w     = (const float*)d_in[6];
    const float* out_b     = (const float*)d_in[7];
    const float* ln1_g     = (const float*)d_in[8];
    const float* ln1_b     = (const float*)d_in[9];
    const float* ln2_g     = (const float*)d_in[10];
    const float* ln2_b     = (const float*)d_in[11];
    const float* ffn_w1    = (const float*)d_in[12];
    const float* ffn_b1    = (const float*)d_in[13];
    const float* ffn_w2    = (const float*)d_in[14];
    const float* ffn_b2    = (const float*)d_in[15];
    const float* edge_w    = (const float*)d_in[16];
    const float* edge_b    = (const float*)d_in[17];
    const float* conv1_w   = (const float*)d_in[18];
    const float* conv1_b   = (const float*)d_in[19];
    const float* conv2_w   = (const float*)d_in[20];
    const float* conv2_b   = (const float*)d_in[21];
    float* out = (float*)d_out;
    float* ws = (float*)d_ws;

    float* h      = ws;                        // 393216
    float* qkv    = h + 393216;                // 1179648
    float* orow   = qkv + 1179648;             // 393216
    float* ocol   = orow + 393216;             // 393216
    float* Pb     = ocol + 393216;             // 1179648
    float* Sb     = Pb + 1179648;              // 6291456
    float* amh    = Sb + 6291456;              // 98304
    float* divacc = amh + 98304;               // 512
    unsigned short* patches16 = (unsigned short*)(divacc + 512);   // 393216
    unsigned short* xl16   = patches16 + 393216;                   // 393216
    unsigned short* hid16  = xl16 + 393216;                        // 1048576
    unsigned short* hfin16 = hid16 + 1048576;                      // 393216
    unsigned short* Wct16  = hfin16 + 393216;                      // 1769472

    im2col_kernel<<<dim3(1536), 256, 0, stream>>>(x, patches16);
    wct_kernel<<<dim3(6912), 256, 0, stream>>>(conv1_w, Wct16);
    gemm_bf16<MB | MPOS | MBF32><<<dim3(12, 8, 1), 256, 0, stream>>>(
        patches16, nullptr, patch_w, patch_b, pos_embed, h, nullptr,
        512, 768, 768, 1, 0, 0, 0, 0);

    for (int l = 0; l < NL; ++l) {
        ln_kernel<<<512, 256, 0, stream>>>(h, ln1_g + l * DIM, ln1_b + l * DIM, xl16);
        gemm_bf16<MB | MBF32><<<dim3(36, 8, 1), 256, 0, stream>>>(
            xl16, nullptr, in_proj_w + (size_t)l * 1769472,
            in_proj_b + (size_t)l * 2304, nullptr, qkv, nullptr,
            512, 2304, 768, 1, 0, 0, 0, 0);
        attn_kernel<<<dim3(BB * GG, 2, NH), 256, 0, stream>>>(
            qkv, orow, ocol, amh + (size_t)l * 12288);
        gemm_bf16<MB2 | MRES | MAS2 | MBF32><<<dim3(12, 8, 1), 256, 0, stream>>>(
            orow, ocol, out_w + (size_t)l * 589824,
            out_b + (size_t)l * DIM, nullptr, h, nullptr,
            512, 768, 768, 1, 0, 0, 0, 0);
        ln_kernel<<<512, 256, 0, stream>>>(h, ln2_g + l * DIM, ln2_b + l * DIM, xl16);
        gemm_bf16<MB | MRELU | MOBF16 | MBF32><<<dim3(32, 8, 1), 256, 0, stream>>>(
            xl16, nullptr, ffn_w1 + (size_t)l * 1572864,
            ffn_b1 + (size_t)l * FFD, nullptr, nullptr, hid16,
            512, 2048, 768, 1, 0, 0, 0, 0);
        gemm_bf16<MB | MRES | MBF32><<<dim3(12, 8, 1), 256, 0, stream>>>(
            hid16, nullptr, ffn_w2 + (size_t)l * 1572864,
            ffn_b2 + (size_t)l * DIM, nullptr, h, nullptr,
            512, 768, 2048, 1, 0, 0, 0, 0);
    }

    divred_kernel<<<dim3(2), 256, 0, stream>>>(amh, divacc);
    hfin_kernel<<<dim3(1536), 256, 0, stream>>>(h, divacc, edge_w, edge_b, hfin16);
    // P[b][dydx][oc][n]: z = dydx*2 + b
    gemm_bf16<0><<<dim3(4, 4, 18), 256, 0, stream>>>(
        Wct16, nullptr, hfin16, nullptr, nullptr, Pb, nullptr, 256, 256, 768,
        2, 196608LL, 196608LL, 65536LL, 589824LL);
    s_kernel<<<dim3(64, 6), 256, 0, stream>>>(Pb, Sb);
    out_kernel<<<dim3(512), 256, 0, stream>>>(Sb, conv1_b, conv2_w, conv2_b, out);
}

// Round 4
// 677.473 us; speedup vs baseline: 3.5771x; 1.0539x over previous
//
#include <hip/hip_runtime.h>
#include <hip/hip_bf16.h>
#include <math.h>

#define BB 2
#define CIN 3
#define IMGS 256
#define PS 16
#define GG 16
#define NN 256
#define DIM 768
#define NH 12
#define NL 8
#define FFD 2048
#define LNEPS 1e-5f

typedef __attribute__((ext_vector_type(8))) short bf16x8;
typedef __attribute__((ext_vector_type(4))) float f32x4;

// ---- gemm mode flags ----
#define MB     1    // add bias[col]
#define MB2    2    // bias * 2 (implies bias)
#define MPOS   4    // add pos_embed[(row%256)*N + col]
#define MRELU  8
#define MRES   16   // C += result (residual, fp32)
#define MOBF16 32   // write bf16 to C16 instead of fp32 C
#define MAS2   64   // A = two fp32 arrays, summed + converted during staging
#define MBF32  128  // B = fp32 array, converted during staging
#define MLNA   256  // A = fp32 + layernorm (stats + g + b) during staging
#define MAIM2  512  // A = raw image x, im2col during staging (fp32)

__device__ inline unsigned short bc(float f) {
    return __builtin_bit_cast(unsigned short, __float2bfloat16(f));
}

__device__ inline void gload16(const unsigned short* g, unsigned short* l) {
    __builtin_amdgcn_global_load_lds((const __attribute__((address_space(1))) void*)g,
                                     (__attribute__((address_space(3))) void*)l, 16, 0, 0);
}

// C[M,N] = A[M,K] * B[N,K]^T + epilogue. Tiles 32x32, 4 waves (2x2, each 16x16).
// 1-D grid of (N/32)*(M/32) blocks, XCD-swizzled: id%8 == bx%8 so all blocks
// sharing a B-panel live on one XCD (per-XCD B footprint < 1MB, L2-resident).
// LDS linear dest; XOR swizzle (chunk ^= row&7) on source index + ds_read side.
template<int MODE>
__global__ __launch_bounds__(256) void gemm_bf16(
    const void* __restrict__ Av, const void* __restrict__ A2v, const void* __restrict__ Bv,
    const float* __restrict__ bias, const float* __restrict__ pos,
    const float2* __restrict__ stats, const float* __restrict__ lng,
    const float* __restrict__ lnb,
    float* __restrict__ C, unsigned short* __restrict__ C16,
    int M, int N, int K, int zdiv,
    long long sAo, long long sBi, long long sCo, long long sCi)
{
    int z = blockIdx.y;
    int zo = z / zdiv, zi = z % zdiv;
    const unsigned short* A16 = (const unsigned short*)Av + (size_t)zo * sAo;
    const float* Af  = (const float*)Av  + (size_t)zo * sAo;
    const float* Af2 = (const float*)A2v + (size_t)zo * sAo;
    const unsigned short* B16 = (const unsigned short*)Bv + (size_t)zi * sBi;
    const float* Bf  = (const float*)Bv  + (size_t)zi * sBi;
    long long coff = (long long)zo * sCo + (long long)zi * sCi;

    // XCD swizzle decode (bijective; NBX % 8 == 0 for all our shapes)
    int NBY = M >> 5;
    int nbysh = 31 - __builtin_clz(NBY);
    int id = blockIdx.x;
    int xcd = id & 7, q = id >> 3;
    int by = q & (NBY - 1), bxh = q >> nbysh;
    int bx = bxh * 8 + xcd;
    int bm = by * 32, bn = bx * 32;

    __shared__ __align__(16) unsigned short As[2][2048], Bs[2][2048];
    int tid = threadIdx.x;
    int lane = tid & 63, wave = tid >> 6;
    int wr = wave >> 1, wc = wave & 1;
    int s = wave * 64 + lane;               // one 16B slot per thread per matrix
    int srow = s >> 3, schk = (s & 7) ^ (srow & 7);

    f32x4 acc = {};
    f32x4 rA0, rA1, rA20, rA21, rB0, rB1, gv0, gv1, bv0, bv1;
    float2 strow;

    auto gstageA = [&](int b, int kt) {
        gload16(A16 + (size_t)(bm + srow) * K + kt * 64 + schk * 8, &As[b][s * 8]);
    };
    auto gstageB = [&](int b, int kt) {
        gload16(B16 + (size_t)(bn + srow) * K + kt * 64 + schk * 8, &Bs[b][s * 8]);
    };
    auto ldA = [&](int kt) {
        int k0 = kt * 64 + schk * 8;
        if constexpr (MODE & MAIM2) {
            int m = bm + srow;
            int bq = m >> 8, n = m & 255, gy = n >> 4, gx = n & 15;
            int c = k0 >> 8, rem = k0 & 255, py = rem >> 4, px = rem & 15;
            const float* src = Af + (((size_t)(bq * CIN + c) * IMGS + gy * PS + py) << 8)
                             + gx * PS + px;
            rA0 = *(const f32x4*)(src);
            rA1 = *(const f32x4*)(src + 4);
        } else {
            size_t off = (size_t)(bm + srow) * K + k0;
            rA0 = *(const f32x4*)(Af + off);
            rA1 = *(const f32x4*)(Af + off + 4);
            if constexpr (MODE & MAS2) {
                rA20 = *(const f32x4*)(Af2 + off);
                rA21 = *(const f32x4*)(Af2 + off + 4);
            }
            if constexpr (MODE & MLNA) {
                strow = stats[bm + srow];
                gv0 = *(const f32x4*)(lng + k0); gv1 = *(const f32x4*)(lng + k0 + 4);
                bv0 = *(const f32x4*)(lnb + k0); bv1 = *(const f32x4*)(lnb + k0 + 4);
            }
        }
    };
    auto ldB = [&](int kt) {
        size_t off = (size_t)(bn + srow) * K + kt * 64 + schk * 8;
        rB0 = *(const f32x4*)(Bf + off);
        rB1 = *(const f32x4*)(Bf + off + 4);
    };
    auto wrA = [&](int b) {
        bf16x8 v;
        #pragma unroll
        for (int j = 0; j < 4; ++j) {
            float x0 = rA0[j], x1 = rA1[j];
            if constexpr (MODE & MAS2) { x0 += rA20[j]; x1 += rA21[j]; }
            if constexpr (MODE & MLNA) {
                x0 = (x0 - strow.x) * strow.y * gv0[j] + bv0[j];
                x1 = (x1 - strow.x) * strow.y * gv1[j] + bv1[j];
            }
            v[j] = (short)bc(x0); v[4 + j] = (short)bc(x1);
        }
        *(bf16x8*)(&As[b][s * 8]) = v;
    };
    auto wrB = [&](int b) {
        bf16x8 v;
        #pragma unroll
        for (int j = 0; j < 4; ++j) {
            v[j] = (short)bc(rB0[j]); v[4 + j] = (short)bc(rB1[j]);
        }
        *(bf16x8*)(&Bs[b][s * 8]) = v;
    };
    constexpr bool regA = (MODE & (MAS2 | MLNA | MAIM2)) != 0;
    auto compute = [&](int b) {
        const unsigned short* Ab = As[b];
        const unsigned short* Bb = Bs[b];
        int rl = lane & 15, kh = lane >> 4;
        #pragma unroll
        for (int ks = 0; ks < 2; ++ks) {
            int kc = ks * 4 + kh;
            int ar = 16 * wr + rl, br = 16 * wc + rl;
            bf16x8 af = *(const bf16x8*)(Ab + ar * 64 + (kc ^ (ar & 7)) * 8);
            bf16x8 bf = *(const bf16x8*)(Bb + br * 64 + (kc ^ (br & 7)) * 8);
            acc = __builtin_amdgcn_mfma_f32_16x16x32_bf16(af, bf, acc, 0, 0, 0);
        }
    };

    int nt = K >> 6;
    if constexpr (!regA) gstageA(0, 0); else { ldA(0); wrA(0); }
    if constexpr (!(MODE & MBF32)) gstageB(0, 0); else { ldB(0); wrB(0); }
    __syncthreads();
    int buf = 0;
    for (int t = 0; t < nt; ++t) {
        if (t + 1 < nt) {
            if constexpr (!regA) gstageA(buf ^ 1, t + 1); else ldA(t + 1);
            if constexpr (!(MODE & MBF32)) gstageB(buf ^ 1, t + 1); else ldB(t + 1);
        }
        compute(buf);
        if (t + 1 < nt) {
            if constexpr (regA) wrA(buf ^ 1);
            if constexpr (MODE & MBF32) wrB(buf ^ 1);
        }
        __syncthreads();
        buf ^= 1;
    }

    #pragma unroll
    for (int r = 0; r < 4; ++r) {
        int row = bm + 16 * wr + (lane >> 4) * 4 + r;
        int col = bn + 16 * wc + (lane & 15);
        float v = acc[r];
        if (MODE & (MB | MB2)) v += bias[col] * ((MODE & MB2) ? 2.f : 1.f);
        if (MODE & MPOS) v += pos[(size_t)(row & (NN - 1)) * N + col];
        if (MODE & MRELU) v = fmaxf(v, 0.f);
        long long ci = coff + (long long)row * N + col;
        if (MODE & MOBF16) C16[ci] = bc(v);
        else if (MODE & MRES) C[ci] += v;
        else C[ci] = v;
    }
}

// Wct16[dydx][oc][c] = bf16(conv1_w[oc][c][dy][dx])
__global__ void wct_kernel(const float* __restrict__ w, unsigned short* __restrict__ Wct)
{
    int idx = blockIdx.x * 256 + threadIdx.x;   // < 1769472
    int c = idx % DIM;
    int t = idx / DIM;
    int oc = t & 255;
    int dydx = t >> 8;
    int dy = dydx / 3, dx = dydx % 3;
    Wct[idx] = bc(w[((size_t)(oc * DIM + c) * 3 + dy) * 3 + dx]);
}

// per-row mean / rsqrt(var): one wave per row, no barriers
__global__ __launch_bounds__(256) void lnstat_kernel(const float* __restrict__ X,
                                                     float2* __restrict__ st)
{
    int row = blockIdx.x * 4 + (threadIdx.x >> 6);
    int lane = threadIdx.x & 63;
    const float* xp = X + (size_t)row * DIM + lane * 4;
    float s = 0.f, s2 = 0.f;
    #pragma unroll
    for (int seg = 0; seg < 3; ++seg) {
        f32x4 v = *(const f32x4*)(xp + seg * 256);
        s += v[0] + v[1] + v[2] + v[3];
        s2 += v[0] * v[0] + v[1] * v[1] + v[2] * v[2] + v[3] * v[3];
    }
    #pragma unroll
    for (int off = 32; off > 0; off >>= 1) {
        s  += __shfl_xor(s, off);
        s2 += __shfl_xor(s2, off);
    }
    if (lane == 0) {
        float mean = s * (1.f / DIM);
        float var = s2 * (1.f / DIM) - mean * mean;
        st[row] = make_float2(mean, rsqrtf(var + LNEPS));
    }
}

// grid (B*G, 2 types, 12 heads). amh slice: [type][b][n][h] (per layer)
__global__ __launch_bounds__(256) void attn_kernel(
    const float* __restrict__ qkv, float* __restrict__ orow,
    float* __restrict__ ocol, float* __restrict__ amh)
{
    int b = blockIdx.x >> 4, g = blockIdx.x & 15;
    int type = blockIdx.y;
    int hh = blockIdx.z;
    int tid = threadIdx.x;
    __shared__ float qs[16][68], ks[16][68], vs[16][68], as_[16][17];
    {
        int sr = tid >> 4, dq = tid & 15;
        int n = (type == 0) ? (sr * GG + g) : (g * GG + sr);
        const float* base = qkv + (size_t)(b * NN + n) * (3 * DIM) + hh * 64 + dq * 4;
        float4 qv = *(const float4*)(base);
        float4 kv = *(const float4*)(base + DIM);
        float4 vv = *(const float4*)(base + 2 * DIM);
        *(float4*)&qs[sr][dq * 4] = qv;
        *(float4*)&ks[sr][dq * 4] = kv;
        *(float4*)&vs[sr][dq * 4] = vv;
    }
    __syncthreads();
    int s = tid >> 4, t = tid & 15;
    float sc = 0.f;
    #pragma unroll
    for (int d = 0; d < 64; ++d) sc += qs[s][d] * ks[t][d];
    sc *= 0.125f;
    float mx = sc;
    #pragma unroll
    for (int off = 1; off < 16; off <<= 1) mx = fmaxf(mx, __shfl_xor(mx, off, 16));
    float p = __expf(sc - mx);
    float sum = p;
    #pragma unroll
    for (int off = 1; off < 16; off <<= 1) sum += __shfl_xor(sum, off, 16);
    as_[s][t] = p / sum;
    __syncthreads();
    if (tid < 16) {
        float a = 0.f;
        #pragma unroll
        for (int ss = 0; ss < 16; ++ss) a += as_[ss][tid];
        amh[((size_t)(type * BB + b) * NN + g * GG + tid) * NH + hh] = a;
    }
    int s2 = tid >> 4, dg = (tid & 15) * 4;
    float o0 = 0, o1 = 0, o2 = 0, o3 = 0;
    #pragma unroll
    for (int t2 = 0; t2 < 16; ++t2) {
        float a2 = as_[s2][t2];
        o0 += a2 * vs[t2][dg];
        o1 += a2 * vs[t2][dg + 1];
        o2 += a2 * vs[t2][dg + 2];
        o3 += a2 * vs[t2][dg + 3];
    }
    int n2 = (type == 0) ? (s2 * GG + g) : (g * GG + s2);
    float* op = ((type == 0) ? orow : ocol) + (size_t)(b * NN + n2) * DIM + hh * 64 + dg;
    *(float4*)op = make_float4(o0, o1, o2, o3);
}

// divacc[b*256+n] = sum_l |rowmean - colmean| / (NH*GG). amh: [L][2][B][256][12]
__global__ void divred_kernel(const float* __restrict__ amh, float* __restrict__ divacc)
{
    int i = blockIdx.x * 256 + threadIdx.x;     // < 512
    int b = i >> 8, n = i & 255;
    float acc = 0.f;
    #pragma unroll
    for (int l = 0; l < NL; ++l) {
        float rs = 0.f, cs = 0.f;
        const float* base = amh + (size_t)l * 12288 + (size_t)b * 3072 + n * 12;
        #pragma unroll
        for (int h = 0; h < NH; ++h) {
            rs += base[h];
            cs += base[6144 + h];
        }
        acc += fabsf(rs - cs);
    }
    divacc[i] = acc * (1.f / (NH * GG));
}

// hfin16 = bf16(h + (divacc/L)*edge_w + edge_b)
__global__ void hfin_kernel(const float* __restrict__ h, const float* __restrict__ divacc,
                            const float* __restrict__ ew, const float* __restrict__ eb,
                            unsigned short* __restrict__ hf)
{
    int idx = blockIdx.x * 256 + threadIdx.x;   // < 393216
    int d = idx % DIM, m = idx / DIM;
    hf[idx] = bc(h[idx] + divacc[m] * (1.f / NL) * ew[d] + eb[d]);
}

// S[b][x][dy][oc][i] = sum over dx,j of ax(x+dx-1, j) * P[b][dy*3+dx][oc][i*16+j]
__global__ __launch_bounds__(256) void s_kernel(const float* __restrict__ P, float* __restrict__ S)
{
    int bdy = blockIdx.y;
    int b = bdy / 3, dy = bdy % 3;
    int ocg = blockIdx.x;
    __shared__ float Pl[3][4][16][17];
    int tid = threadIdx.x;
    #pragma unroll
    for (int l = 0; l < 12; ++l) {
        int e = l * 256 + tid;
        int dx = e >> 10, rem = e & 1023;
        int oc = rem >> 8, pix = rem & 255;
        int i = pix >> 4, j = pix & 15;
        Pl[dx][oc][j][i] =
            P[(((size_t)b * 9 + dy * 3 + dx) * 256 + ocg * 4 + oc) * 256 + pix];
    }
    __syncthreads();
    int xq = tid >> 6, oc = (tid >> 4) & 3, i = tid & 15;
    for (int xx = 0; xx < 64; ++xx) {
        int x = xq * 64 + xx;
        float acc = 0.f;
        #pragma unroll
        for (int dx = 0; dx < 3; ++dx) {
            int u = x + dx - 1;
            float p = (u + 0.5f) * 0.0625f - 0.5f;
            float fl = floorf(p);
            float f = p - fl;
            int j0 = (int)fl;
            int ja = j0 < 0 ? 0 : j0;
            int jb = (j0 + 1 > 15) ? 15 : (j0 + 1);
            bool valid = (u >= 0) && (u <= 255);
            float w0 = valid ? 1.f - f : 0.f;
            float w1 = valid ? f : 0.f;
            acc += w0 * Pl[dx][oc][ja][i] + w1 * Pl[dx][oc][jb][i];
        }
        S[(((size_t)(b * 256 + x) * 3 + dy) * 256 + ocg * 4 + oc) * 16 + i] = acc;
    }
}

// out[b][y][x]; S slab per (b,x): [dy][oc][i] = 3*256*16
__global__ __launch_bounds__(256) void out_kernel(
    const float* __restrict__ S, const float* __restrict__ b1,
    const float* __restrict__ w2, const float* __restrict__ b2p,
    float* __restrict__ out)
{
    int b = blockIdx.x >> 8, x = blockIdx.x & 255;
    __shared__ float Sl[12288];
    const float* Sp = S + (size_t)(b * 256 + x) * 12288;
    for (int l = threadIdx.x; l < 12288; l += 256) Sl[l] = Sp[l];
    __syncthreads();
    int y = threadIdx.x;
    float wy[3][2];
    int iy[3][2];
    #pragma unroll
    for (int dy = 0; dy < 3; ++dy) {
        int v = y + dy - 1;
        if (v < 0 || v > 255) {
            wy[dy][0] = wy[dy][1] = 0.f;
            iy[dy][0] = iy[dy][1] = 0;
        } else {
            float pp = (v + 0.5f) * 0.0625f - 0.5f;
            float fl = floorf(pp);
            float f = pp - fl;
            int i0 = (int)fl;
            iy[dy][0] = i0 < 0 ? 0 : i0;
            iy[dy][1] = (i0 + 1 > 15) ? 15 : (i0 + 1);
            wy[dy][0] = 1.f - f;
            wy[dy][1] = f;
        }
    }
    float acc = 0.f;
    for (int oc = 0; oc < 256; ++oc) {
        float sv = 0.f;
        #pragma unroll
        for (int dy = 0; dy < 3; ++dy)
            sv += wy[dy][0] * Sl[dy * 4096 + oc * 16 + iy[dy][0]]
                + wy[dy][1] * Sl[dy * 4096 + oc * 16 + iy[dy][1]];
        sv += b1[oc];
        acc += fmaxf(sv, 0.f) * w2[oc];
    }
    out[(size_t)b * 65536 + y * 256 + x] = acc + b2p[0];
}

extern "C" void kernel_launch(void* const* d_in, const int* in_sizes, int n_in,
                              void* d_out, int out_size, void* d_ws, size_t ws_size,
                              hipStream_t stream)
{
    const float* x         = (const float*)d_in[0];
    const float* patch_w   = (const float*)d_in[1];
    const float* patch_b   = (const float*)d_in[2];
    const float* pos_embed = (const float*)d_in[3];
    const float* in_proj_w = (const float*)d_in[4];
    const float* in_proj_b = (const float*)d_in[5];
    const float* out_w     = (const float*)d_in[6];
    const float* out_b     = (const float*)d_in[7];
    const float* ln1_g     = (const float*)d_in[8];
    const float* ln1_b     = (const float*)d_in[9];
    const float* ln2_g     = (const float*)d_in[10];
    const float* ln2_b     = (const float*)d_in[11];
    const float* ffn_w1    = (const float*)d_in[12];
    const float* ffn_b1    = (const float*)d_in[13];
    const float* ffn_w2    = (const float*)d_in[14];
    const float* ffn_b2    = (const float*)d_in[15];
    const float* edge_w    = (const float*)d_in[16];
    const float* edge_b    = (const float*)d_in[17];
    const float* conv1_w   = (const float*)d_in[18];
    const float* conv1_b   = (const float*)d_in[19];
    const float* conv2_w   = (const float*)d_in[20];
    const float* conv2_b   = (const float*)d_in[21];
    float* out = (float*)d_out;
    float* ws = (float*)d_ws;

    float* h      = ws;                        // 393216
    float* qkv    = h + 393216;                // 1179648
    float* orow   = qkv + 1179648;             // 393216
    float* ocol   = orow + 393216;             // 393216
    float* Pb     = ocol + 393216;             // 1179648
    float* Sb     = Pb + 1179648;              // 6291456
    float* amh    = Sb + 6291456;              // 98304
    float* divacc = amh + 98304;               // 512
    float2* stats = (float2*)(divacc + 512);   // 512 float2 = 1024 floats
    unsigned short* hid16  = (unsigned short*)(divacc + 512 + 1024);   // 1048576
    unsigned short* hfin16 = hid16 + 1048576;                          // 393216
    unsigned short* Wct16  = hfin16 + 393216;                          // 1769472

    wct_kernel<<<dim3(6912), 256, 0, stream>>>(conv1_w, Wct16);
    // patch embed: A = x via im2col (fp32), B = patch_w (fp32). grid 24x16
    gemm_bf16<MB | MPOS | MAIM2 | MBF32><<<dim3(24 * 16), 256, 0, stream>>>(
        x, nullptr, patch_w, patch_b, pos_embed, nullptr, nullptr, nullptr,
        h, nullptr, 512, 768, 768, 1, 0, 0, 0, 0);

    for (int l = 0; l < NL; ++l) {
        lnstat_kernel<<<dim3(128), 256, 0, stream>>>(h, stats);
        gemm_bf16<MB | MLNA | MBF32><<<dim3(72 * 16), 256, 0, stream>>>(
            h, nullptr, in_proj_w + (size_t)l * 1769472,
            in_proj_b + (size_t)l * 2304, nullptr, stats,
            ln1_g + l * DIM, ln1_b + l * DIM, qkv, nullptr,
            512, 2304, 768, 1, 0, 0, 0, 0);
        attn_kernel<<<dim3(BB * GG, 2, NH), 256, 0, stream>>>(
            qkv, orow, ocol, amh + (size_t)l * 12288);
        gemm_bf16<MB2 | MRES | MAS2 | MBF32><<<dim3(24 * 16), 256, 0, stream>>>(
            orow, ocol, out_w + (size_t)l * 589824,
            out_b + (size_t)l * DIM, nullptr, nullptr, nullptr, nullptr,
            h, nullptr, 512, 768, 768, 1, 0, 0, 0, 0);
        lnstat_kernel<<<dim3(128), 256, 0, stream>>>(h, stats);
        gemm_bf16<MB | MRELU | MOBF16 | MLNA | MBF32><<<dim3(64 * 16), 256, 0, stream>>>(
            h, nullptr, ffn_w1 + (size_t)l * 1572864,
            ffn_b1 + (size_t)l * FFD, nullptr, stats,
            ln2_g + l * DIM, ln2_b + l * DIM, nullptr, hid16,
            512, 2048, 768, 1, 0, 0, 0, 0);
        gemm_bf16<MB | MRES | MBF32><<<dim3(24 * 16), 256, 0, stream>>>(
            hid16, nullptr, ffn_w2 + (size_t)l * 1572864,
            ffn_b2 + (size_t)l * DIM, nullptr, nullptr, nullptr, nullptr,
            h, nullptr, 512, 768, 2048, 1, 0, 0, 0, 0);
    }

    divred_kernel<<<dim3(2), 256, 0, stream>>>(amh, divacc);
    hfin_kernel<<<dim3(1536), 256, 0, stream>>>(h, divacc, edge_w, edge_b, hfin16);
    // P[b][dydx][oc][n]: z = dydx*2 + b, grid (8x8, 18)
    gemm_bf16<0><<<dim3(8 * 8, 18), 256, 0, stream>>>(
        Wct16, nullptr, hfin16, nullptr, nullptr, nullptr, nullptr, nullptr,
        Pb, nullptr, 256, 256, 768,
        2, 196608LL, 196608LL, 65536LL, 589824LL);
    s_kernel<<<dim3(64, 6), 256, 0, stream>>>(Pb, Sb);
    out_kernel<<<dim3(512), 256, 0, stream>>>(Sb, conv1_b, conv2_w, conv2_b, out);
}